// Round 9
// baseline (737.709 us; speedup 1.0000x reference)
//
#include <hip/hip_runtime.h>
#include <hip/hip_bf16.h>
#include <cstdint>

#define AS_GLOBAL __attribute__((address_space(1)))
#define AS_LDS    __attribute__((address_space(3)))

typedef __attribute__((ext_vector_type(8))) short bf16x8;
typedef __attribute__((ext_vector_type(8))) unsigned short u16x8;
typedef __attribute__((ext_vector_type(4))) float f32x4;

static __device__ __forceinline__ ushort f2bf(float x) {
    union { float f; uint32_t u; } c;
    c.f = x;
    uint32_t u = c.u;
    u += 0x7fffu + ((u >> 16) & 1u);   // RTNE
    return (ushort)(u >> 16);
}
static __device__ __forceinline__ float bf2f(ushort u) {
    union { uint32_t i; float f; } c;
    c.i = ((uint32_t)u) << 16;
    return c.f;
}

// async global->LDS, 16B/lane. Dest = wave-uniform base + lane*16.
static __device__ __forceinline__ void gload_lds16(const void* g, void* l) {
    __builtin_amdgcn_global_load_lds(
        (const AS_GLOBAL uint32_t*)(uintptr_t)g,
        (AS_LDS uint32_t*)(uint32_t)(uintptr_t)l,
        16, 0, 0);
}

// ---------------- [K,N] fp32 -> [N,K] bf16 transpose (4 weights, z-indexed) ----------------
__global__ __launch_bounds__(256)
void transpose4_to_bf16(const float* __restrict__ w0, const float* __restrict__ w1,
                        const float* __restrict__ w2, const float* __restrict__ w3,
                        ushort* __restrict__ t0, ushort* __restrict__ t1,
                        ushort* __restrict__ t2, ushort* __restrict__ t3) {
    const int K = 1024, N = 1024;
    __shared__ float tile[32][33];
    const float* w; ushort* wt;
    switch (blockIdx.z) {
        case 0: w = w0; wt = t0; break;
        case 1: w = w1; wt = t1; break;
        case 2: w = w2; wt = t2; break;
        default: w = w3; wt = t3; break;
    }
    int bn = blockIdx.x * 32;
    int bk = blockIdx.y * 32;
    int tx = threadIdx.x & 31, ty = threadIdx.x >> 5;
    #pragma unroll
    for (int i = 0; i < 32; i += 8)
        tile[ty + i][tx] = w[(size_t)(bk + ty + i) * N + bn + tx];
    __syncthreads();
    #pragma unroll
    for (int i = 0; i < 32; i += 8)
        wt[(size_t)(bn + ty + i) * K + bk + tx] = f2bf(tile[tx][ty + i]);
}

// =====================================================================
// 128x128 GEMM, 4 waves, BK=32.
// A_F32=0 (final GEMM): exact r8 structure — bf16 A+B via gload_lds,
//   3-deep ring staged 2 ahead, counted vmcnt(4), XOR-slot swizzle, 0 conflicts.
// A_F32=1 (projections): A staged as fp32 via gload_lds (2-deep, 32KB) with
//   16B-slot XOR (phys = logical ^ (row&7)); bf16 cvt at frag-read time
//   (consumer side, hidden under MFMA). B 2-deep. 48KB total -> 3 blocks/CU.
//   Stage-at-top + vmcnt(0) drain after compute (m97-style).
// C[M,1024] = A[M,1024] * Bt[1024,1024](bf16).
// EPI: 0=none 1=sigmoid 2=exp.  OUT_BF: bf16 C.
// =====================================================================
template<int EPI, int A_F32, int OUT_BF>
__global__ __launch_bounds__(256)
void gemm128(const void* __restrict__ Av, const ushort* __restrict__ Bt,
             void* __restrict__ Cv) {
    constexpr int K = 1024, N = 1024;
    constexpr int A_TUS = A_F32 ? 8192 : 4096;   // ushorts per A tile (16KB fp32 / 8KB bf16)
    constexpr int DEPTH = A_F32 ? 2 : 3;
    __shared__ alignas(16) ushort sA[DEPTH * A_TUS];
    __shared__ alignas(16) ushort sB[DEPTH * 4096];
    const int tid  = threadIdx.x;
    const int wid  = tid >> 6;
    const int lane = tid & 63;
    const int wr = wid >> 1, wc = wid & 1;       // 2x2 waves of 64x64
    const int lr = lane & 15;
    const int kb = lane >> 4;                    // logical k-slot 0..3

    // XCD-locality swizzle (r7/r8-verified: FETCH 265->65 MB):
    const int wg = blockIdx.x;
    const int xcd = wg & 7, local = wg >> 3;
    const int bm = xcd * 32 + (local >> 3);
    const int bn = local & 7;
    const int m0 = bm * 128, n0 = bn * 128;

    const float*  Af = (const float*)Av;
    const ushort* Ab = (const ushort*)Av;

    f32x4 acc[4][4] = {};

    auto stageA = [&](int tile, int buf) {
        const int kt0 = tile * 32;
        if constexpr (A_F32) {
            float* dst = (float*)&sA[buf * A_TUS];
            #pragma unroll
            for (int j = 0; j < 4; j++) {
                int c = j * 256 + tid;           // 16B chunk id, 1024 total
                int r = c >> 3, p = c & 7;
                int s = p ^ (r & 7);             // pre-swizzled source
                gload_lds16(Af + (size_t)(m0 + r) * K + kt0 + s * 4, dst + c * 4);
            }
        } else {
            ushort* dst = &sA[buf * A_TUS];
            #pragma unroll
            for (int j = 0; j < 2; j++) {
                int c = j * 256 + tid;           // 512 chunks
                int r = c >> 2, p = c & 3;
                int s = p ^ ((r >> 1) & 3);
                gload_lds16(Ab + (size_t)(m0 + r) * K + kt0 + s * 8, dst + c * 8);
            }
        }
    };
    auto stageBf = [&](int tile, int buf) {
        ushort* dst = &sB[buf * 4096];
        const int kt0 = tile * 32;
        #pragma unroll
        for (int j = 0; j < 2; j++) {
            int c = j * 256 + tid;
            int r = c >> 2, p = c & 3;
            int s = p ^ ((r >> 1) & 3);
            gload_lds16(Bt + (size_t)(n0 + r) * K + kt0 + s * 8, dst + c * 8);
        }
    };
    auto compute = [&](int buf) {
        bf16x8 af[4], bv[4];
        const int xs = (lr >> 1) & 3;
        if constexpr (A_F32) {
            const float* pAf = (const float*)&sA[buf * A_TUS];
            #pragma unroll
            for (int m = 0; m < 4; m++) {
                int r = wr * 64 + m * 16 + lr;
                int q0 = (2 * kb) ^ (r & 7);
                int q1 = (2 * kb + 1) ^ (r & 7);
                f32x4 a0 = *(const f32x4*)&pAf[r * 32 + q0 * 4];
                f32x4 a1 = *(const f32x4*)&pAf[r * 32 + q1 * 4];
                bf16x8 t;
                t[0]=(short)f2bf(a0[0]); t[1]=(short)f2bf(a0[1]);
                t[2]=(short)f2bf(a0[2]); t[3]=(short)f2bf(a0[3]);
                t[4]=(short)f2bf(a1[0]); t[5]=(short)f2bf(a1[1]);
                t[6]=(short)f2bf(a1[2]); t[7]=(short)f2bf(a1[3]);
                af[m] = t;
            }
        } else {
            const ushort* pA = &sA[buf * A_TUS];
            #pragma unroll
            for (int m = 0; m < 4; m++)
                af[m] = *(const bf16x8*)&pA[(wr * 64 + m * 16 + lr) * 32 + (kb ^ xs) * 8];
        }
        const ushort* pB = &sB[buf * 4096];
        #pragma unroll
        for (int n = 0; n < 4; n++)
            bv[n] = *(const bf16x8*)&pB[(wc * 64 + n * 16 + lr) * 32 + (kb ^ xs) * 8];
        #pragma unroll
        for (int m = 0; m < 4; m++)
            #pragma unroll
            for (int n = 0; n < 4; n++)
                acc[m][n] = __builtin_amdgcn_mfma_f32_16x16x32_bf16(af[m], bv[n], acc[m][n], 0, 0, 0);
    };

    if constexpr (A_F32) {
        // ---- 2-deep drain pipeline ----
        stageA(0, 0); stageBf(0, 0);
        asm volatile("s_waitcnt vmcnt(0)" ::: "memory");
        __builtin_amdgcn_s_barrier();
        asm volatile("" ::: "memory");
        for (int t = 0; t < 32; t++) {
            if (t < 31) { stageA(t + 1, (t + 1) & 1); stageBf(t + 1, (t + 1) & 1); }
            compute(t & 1);
            if (t < 31) asm volatile("s_waitcnt vmcnt(0)" ::: "memory");
            asm volatile("s_waitcnt lgkmcnt(0)" ::: "memory");  // frag reads drained
            __builtin_amdgcn_s_barrier();
            asm volatile("" ::: "memory");
        }
    } else {
        // ---- r8-exact 3-deep counted pipeline ----
        stageA(0, 0); stageBf(0, 0);
        stageA(1, 1); stageBf(1, 1);
        asm volatile("s_waitcnt vmcnt(4)" ::: "memory");   // tile0 done; tile1 in flight
        __builtin_amdgcn_s_barrier();
        asm volatile("" ::: "memory");
        for (int t = 0; t < 32; t++) {
            const int bc = t % 3;
            if (t < 30) { int b2 = (t + 2) % 3; stageA(t + 2, b2); stageBf(t + 2, b2); }
            compute(bc);
            if (t < 30)       asm volatile("s_waitcnt vmcnt(4)" ::: "memory");
            else if (t == 30) asm volatile("s_waitcnt vmcnt(0)" ::: "memory");
            asm volatile("s_waitcnt lgkmcnt(0)" ::: "memory");
            __builtin_amdgcn_s_barrier();
            asm volatile("" ::: "memory");
        }
    }

    // ---- epilogue (C/D: col=lane&15, row=(lane>>4)*4+r) ----
    float*  Cf = (float*)Cv;
    ushort* Cb = (ushort*)Cv;
    #pragma unroll
    for (int m = 0; m < 4; m++) {
        #pragma unroll
        for (int n = 0; n < 4; n++) {
            #pragma unroll
            for (int r = 0; r < 4; r++) {
                int row = m0 + wr * 64 + m * 16 + (lane >> 4) * 4 + r;
                int col = n0 + wc * 64 + n * 16 + (lane & 15);
                float v = acc[m][n][r];
                if (EPI == 1) v = 1.0f / (1.0f + __expf(-v));
                else if (EPI == 2) v = __expf(v);
                size_t idx = (size_t)row * N + col;
                if (OUT_BF) Cb[idx] = f2bf(v);
                else        Cf[idx] = v;
            }
        }
    }
}

// ---------------- scan pass A: per-chunk sums (bf16 in, 16B loads) ----------------
__global__ __launch_bounds__(256)
void scan_partials(const ushort* __restrict__ ke, const ushort* __restrict__ ev,
                   float* __restrict__ pke, float* __restrict__ pkv) {
    const int H = 1024, S = 8192, CHUNK = 32, BH = 4096;
    int c  = blockIdx.x * 2 + (threadIdx.x >> 7);
    int h0 = (threadIdx.x & 127) * 8;
    int b  = blockIdx.y;
    size_t base = ((size_t)b * S + (size_t)c * CHUNK) * H + h0;
    float se[8] = {}, sv[8] = {};
    for (int s = 0; s < CHUNK; s++) {
        u16x8 e8 = *(const u16x8*)(ke + base + (size_t)s * H);
        u16x8 v8 = *(const u16x8*)(ev + base + (size_t)s * H);
        #pragma unroll
        for (int i = 0; i < 8; i++) {
            float e = bf2f(e8[i]);
            se[i] += e;
            sv[i] += e * bf2f(v8[i]);
        }
    }
    size_t p = (size_t)c * BH + b * H + h0;
    *(float4*)(pke + p)     = make_float4(se[0], se[1], se[2], se[3]);
    *(float4*)(pke + p + 4) = make_float4(se[4], se[5], se[6], se[7]);
    *(float4*)(pkv + p)     = make_float4(sv[0], sv[1], sv[2], sv[3]);
    *(float4*)(pkv + p + 4) = make_float4(sv[4], sv[5], sv[6], sv[7]);
}

// ---------------- scan pass B: exclusive prefix over chunks ----------------
__global__ __launch_bounds__(256)
void scan_offsets(float* __restrict__ pke, float* __restrict__ pkv, int nch, int BH) {
    int i = blockIdx.x * blockDim.x + threadIdx.x;
    if (i >= BH) return;
    float rke = 0.f, rkv = 0.f;
    for (int c = 0; c < nch; c++) {
        size_t idx = (size_t)c * BH + i;
        float a = pke[idx], b = pkv[idx];
        pke[idx] = rke; pkv[idx] = rkv;
        rke += a; rkv += b;
    }
}

// ---------------- scan pass C: inclusive scan + y = sigmoid(emb_q)*(kv/ke) ----------------
__global__ __launch_bounds__(256)
void scan_final(const ushort* __restrict__ ke, const ushort* __restrict__ ev,
                const ushort* __restrict__ sq,
                const float* __restrict__ pke, const float* __restrict__ pkv,
                ushort* __restrict__ ybf) {
    const int H = 1024, S = 8192, CHUNK = 32, BH = 4096;
    int c  = blockIdx.x * 2 + (threadIdx.x >> 7);
    int h0 = (threadIdx.x & 127) * 8;
    int b  = blockIdx.y;
    size_t p = (size_t)c * BH + b * H + h0;
    float rke[8], rkv[8];
    *(float4*)(rke)     = *(const float4*)(pke + p);
    *(float4*)(rke + 4) = *(const float4*)(pke + p + 4);
    *(float4*)(rkv)     = *(const float4*)(pkv + p);
    *(float4*)(rkv + 4) = *(const float4*)(pkv + p + 4);
    size_t base = ((size_t)b * S + (size_t)c * CHUNK) * H + h0;
    for (int s = 0; s < CHUNK; s++) {
        size_t idx = base + (size_t)s * H;
        u16x8 e8 = *(const u16x8*)(ke + idx);
        u16x8 v8 = *(const u16x8*)(ev + idx);
        u16x8 q8 = *(const u16x8*)(sq + idx);
        u16x8 o;
        #pragma unroll
        for (int i = 0; i < 8; i++) {
            float e = bf2f(e8[i]);
            rke[i] += e;
            rkv[i] += e * bf2f(v8[i]);
            o[i] = f2bf(bf2f(q8[i]) * (rkv[i] / rke[i]));
        }
        *(u16x8*)(ybf + idx) = o;
    }
}

extern "C" void kernel_launch(void* const* d_in, const int* in_sizes, int n_in,
                              void* d_out, int out_size, void* d_ws, size_t ws_size,
                              hipStream_t stream) {
    const float* q   = (const float*)d_in[0];
    const float* k   = (const float*)d_in[1];
    const float* v   = (const float*)d_in[2];
    const float* w_q = (const float*)d_in[3];
    const float* w_k = (const float*)d_in[4];
    const float* w_v = (const float*)d_in[5];
    const float* w_p = (const float*)d_in[6];
    float* out = (float*)d_out;

    const int B = 4, S = 8192, H = 1024;
    const int M = B * S;                  // 32768
    const size_t MH = (size_t)M * H;      // 33,554,432
    const int NCH = 256;                  // CHUNK = 32
    const int BH = B * H;                 // 4096

    char* ws = (char*)d_ws;
    size_t off = 0;
    auto alloc = [&](size_t bytes) -> char* {
        char* p = ws + off;
        off += (bytes + 255) & ~(size_t)255;
        return p;
    };
    ushort* ybuf = (ushort*)alloc(MH * 2);
    ushort* wqt  = (ushort*)alloc((size_t)H * H * 2);
    ushort* wkt  = (ushort*)alloc((size_t)H * H * 2);
    ushort* wvt  = (ushort*)alloc((size_t)H * H * 2);
    ushort* wpt  = (ushort*)alloc((size_t)H * H * 2);
    ushort* sqb  = (ushort*)alloc(MH * 2);
    ushort* keb  = (ushort*)alloc(MH * 2);
    ushort* evb  = (ushort*)alloc(MH * 2);
    float*  pke  = (float*)alloc((size_t)NCH * BH * 4);
    float*  pkv  = (float*)alloc((size_t)NCH * BH * 4);

    const int ngg = (M / 128) * (H / 128);   // 2048 blocks, swizzled in-kernel
    dim3 tg(H / 32, H / 32, 4);
    dim3 gs(NCH / 2, B);

    transpose4_to_bf16<<<tg, 256, 0, stream>>>(w_q, w_k, w_v, w_p, wqt, wkt, wvt, wpt);

    // projections: fp32 A read directly via gload_lds, cvt at frag-read; fused epilogue
    gemm128<1, 1, 1><<<ngg, 256, 0, stream>>>(q, wqt, sqb);
    gemm128<2, 1, 1><<<ngg, 256, 0, stream>>>(k, wkt, keb);
    gemm128<0, 1, 1><<<ngg, 256, 0, stream>>>(v, wvt, evb);

    // hierarchical scan over S
    scan_partials<<<gs, 256, 0, stream>>>(keb, evb, pke, pkv);
    scan_offsets<<<BH / 256, 256, 0, stream>>>(pke, pkv, NCH, BH);
    scan_final<<<gs, 256, 0, stream>>>(keb, evb, sqb, pke, pkv, ybuf);

    // out = y @ w_p (bf16 A via r8 path, fp32 out)
    gemm128<0, 0, 0><<<ngg, 256, 0, stream>>>(ybuf, wpt, out);
}

// Round 10
// 600.274 us; speedup vs baseline: 1.2290x; 1.2290x over previous
//
#include <hip/hip_runtime.h>
#include <hip/hip_bf16.h>
#include <cstdint>

#define AS_GLOBAL __attribute__((address_space(1)))
#define AS_LDS    __attribute__((address_space(3)))

typedef __attribute__((ext_vector_type(8))) short bf16x8;
typedef __attribute__((ext_vector_type(8))) unsigned short u16x8;
typedef __attribute__((ext_vector_type(4))) float f32x4;

static __device__ __forceinline__ ushort f2bf(float x) {
    union { float f; uint32_t u; } c;
    c.f = x;
    uint32_t u = c.u;
    u += 0x7fffu + ((u >> 16) & 1u);   // RTNE
    return (ushort)(u >> 16);
}
static __device__ __forceinline__ float bf2f(ushort u) {
    union { uint32_t i; float f; } c;
    c.i = ((uint32_t)u) << 16;
    return c.f;
}

// async global->LDS, 16B/lane. Dest = wave-uniform base + lane*16.
static __device__ __forceinline__ void gload_lds16(const void* g, void* l) {
    __builtin_amdgcn_global_load_lds(
        (const AS_GLOBAL uint32_t*)(uintptr_t)g,
        (AS_LDS uint32_t*)(uint32_t)(uintptr_t)l,
        16, 0, 0);
}

// ---------------- fp32 -> bf16 convert, 3 tensors in one dispatch ----------------
__global__ __launch_bounds__(256)
void cvt3_f32_bf16(const float4* __restrict__ in0, const float4* __restrict__ in1,
                   const float4* __restrict__ in2,
                   u16x8* __restrict__ o0, u16x8* __restrict__ o1, u16x8* __restrict__ o2,
                   int n8) {
    const float4* in; u16x8* out;
    switch (blockIdx.y) {
        case 0: in = in0; out = o0; break;
        case 1: in = in1; out = o1; break;
        default: in = in2; out = o2; break;
    }
    int i = blockIdx.x * 256 + threadIdx.x;
    int stride = gridDim.x * 256;
    for (; i < n8; i += stride) {
        float4 a = in[i * 2], b = in[i * 2 + 1];
        u16x8 o;
        o[0] = f2bf(a.x); o[1] = f2bf(a.y); o[2] = f2bf(a.z); o[3] = f2bf(a.w);
        o[4] = f2bf(b.x); o[5] = f2bf(b.y); o[6] = f2bf(b.z); o[7] = f2bf(b.w);
        out[i] = o;
    }
}

// ---------------- [K,N] fp32 -> [N,K] bf16 transpose (4 weights, z-indexed) ----------------
__global__ __launch_bounds__(256)
void transpose4_to_bf16(const float* __restrict__ w0, const float* __restrict__ w1,
                        const float* __restrict__ w2, const float* __restrict__ w3,
                        ushort* __restrict__ t0, ushort* __restrict__ t1,
                        ushort* __restrict__ t2, ushort* __restrict__ t3) {
    const int K = 1024, N = 1024;
    __shared__ float tile[32][33];
    const float* w; ushort* wt;
    switch (blockIdx.z) {
        case 0: w = w0; wt = t0; break;
        case 1: w = w1; wt = t1; break;
        case 2: w = w2; wt = t2; break;
        default: w = w3; wt = t3; break;
    }
    int bn = blockIdx.x * 32;
    int bk = blockIdx.y * 32;
    int tx = threadIdx.x & 31, ty = threadIdx.x >> 5;
    #pragma unroll
    for (int i = 0; i < 32; i += 8)
        tile[ty + i][tx] = w[(size_t)(bk + ty + i) * N + bn + tx];
    __syncthreads();
    #pragma unroll
    for (int i = 0; i < 32; i += 8)
        wt[(size_t)(bn + ty + i) * K + bk + tx] = f2bf(tile[tx][ty + i]);
}

// =====================================================================
// 256x128 GEMM, 4 waves (2M x 2N), wave tile 128x64, BK=32.
// Rationale (r9 post-mortem): the 2-phase GEMM is LDS-BW-bound; wave tile
// 128x64 cuts LDS bytes/FLOP by 28% vs 64x64 (r8) at the same per-CU LDS
// instruction rate. All pipeline machinery is r8's proven version:
// gload_lds both operands, 3-deep ring staged 2 ahead, counted vmcnt(6),
// XOR-slot swizzle (0 conflicts), lgkmcnt(0) + one barrier per step.
// LDS 72KB -> 2 blocks/CU. acc 128 AGPR -> launch_bounds(256,2).
// C[M,1024] = A[M,1024](bf16) * Bt[1024,1024](bf16).
// EPI: 0=none 1=sigmoid 2=exp.  OUT_BF: bf16 C.
// =====================================================================
template<int EPI, int OUT_BF>
__global__ __launch_bounds__(256, 2)
void gemm256x128(const ushort* __restrict__ A, const ushort* __restrict__ Bt,
                 void* __restrict__ Cv) {
    constexpr int K = 1024, N = 1024;
    __shared__ alignas(16) ushort sA[3 * 8192];   // 3 x 16KB (256 rows x 32)
    __shared__ alignas(16) ushort sB[3 * 4096];   // 3 x 8KB  (128 rows x 32)
    const int tid  = threadIdx.x;
    const int wid  = tid >> 6;
    const int lane = tid & 63;
    const int wr = wid >> 1, wc = wid & 1;        // 2x2 waves; wave tile 128x64
    const int lr = lane & 15;
    const int kb = lane >> 4;                     // logical k-slot 0..3
    const int xs = (lr >> 1) & 3;                 // read-side XOR

    // XCD-locality swizzle: 1024 wgs = 8 xcds x 128; consecutive locals on one
    // XCD cycle bn (8 values) sharing an A-panel.
    const int wg = blockIdx.x;
    const int xcd = wg & 7, local = wg >> 3;
    const int bm = xcd * 16 + (local >> 3);       // 128 m-panels = 8 xcds x 16
    const int bn = local & 7;
    const int m0 = bm * 256, n0 = bn * 128;

    f32x4 acc[8][4] = {};

    // ---- staging: 6 gloads/thread (A x4, B x2); source pre-swizzled so that
    // phys 16B-slot p of row r holds logical slot p ^ ((r>>1)&3).
    auto stage = [&](int tile, int buf) {
        const int kt0 = tile * 32;
        ushort* dA = &sA[buf * 8192];
        ushort* dB = &sB[buf * 4096];
        #pragma unroll
        for (int j = 0; j < 4; j++) {
            int c = j * 256 + tid;                // 1024 chunks (256 rows x 4 slots)
            int r = c >> 2, p = c & 3;
            int s = p ^ ((r >> 1) & 3);
            gload_lds16(A + (size_t)(m0 + r) * K + kt0 + s * 8, dA + c * 8);
        }
        #pragma unroll
        for (int j = 0; j < 2; j++) {
            int c = j * 256 + tid;                // 512 chunks (128 rows x 4 slots)
            int r = c >> 2, p = c & 3;
            int s = p ^ ((r >> 1) & 3);
            gload_lds16(Bt + (size_t)(n0 + r) * K + kt0 + s * 8, dB + c * 8);
        }
    };
    // ---- compute one BK=32 step; XOR-deswizzled reads (conflict-free, r8-verified) ----
    auto compute = [&](int buf) {
        const ushort* pA = &sA[buf * 8192];
        const ushort* pB = &sB[buf * 4096];
        bf16x8 af[8], bv[4];
        #pragma unroll
        for (int m = 0; m < 8; m++)
            af[m] = *(const bf16x8*)&pA[(wr * 128 + m * 16 + lr) * 32 + (kb ^ xs) * 8];
        #pragma unroll
        for (int n = 0; n < 4; n++)
            bv[n] = *(const bf16x8*)&pB[(wc * 64 + n * 16 + lr) * 32 + (kb ^ xs) * 8];
        #pragma unroll
        for (int m = 0; m < 8; m++)
            #pragma unroll
            for (int n = 0; n < 4; n++)
                acc[m][n] = __builtin_amdgcn_mfma_f32_16x16x32_bf16(af[m], bv[n], acc[m][n], 0, 0, 0);
    };

    // ---- prologue: stage tiles 0,1 ----
    stage(0, 0);
    stage(1, 1);
    asm volatile("s_waitcnt vmcnt(6)" ::: "memory");   // tile0 done; tile1 in flight
    __builtin_amdgcn_s_barrier();
    asm volatile("" ::: "memory");

    // ---- main loop: 32 K-steps, one barrier each ----
    // queue at step t's wait: [tile(t+1) x6, tile(t+2) x6] -> vmcnt(6) drains t+1.
    // WAR: stage(t+2) overwrites the buf read at t-1, drained at t-1's
    // lgkmcnt(0)+barrier.
    for (int t = 0; t < 32; t++) {
        if (t < 30) stage(t + 2, (t + 2) % 3);
        compute(t % 3);
        if (t < 30)       asm volatile("s_waitcnt vmcnt(6)" ::: "memory");
        else if (t == 30) asm volatile("s_waitcnt vmcnt(0)" ::: "memory");
        asm volatile("s_waitcnt lgkmcnt(0)" ::: "memory");  // frag reads drained
        __builtin_amdgcn_s_barrier();
        asm volatile("" ::: "memory");
    }

    // ---- epilogue (C/D: col=lane&15, row=(lane>>4)*4+r) ----
    float*  Cf = (float*)Cv;
    ushort* Cb = (ushort*)Cv;
    #pragma unroll
    for (int m = 0; m < 8; m++) {
        #pragma unroll
        for (int n = 0; n < 4; n++) {
            #pragma unroll
            for (int r = 0; r < 4; r++) {
                int row = m0 + wr * 128 + m * 16 + (lane >> 4) * 4 + r;
                int col = n0 + wc * 64 + n * 16 + (lane & 15);
                float v = acc[m][n][r];
                if (EPI == 1) v = 1.0f / (1.0f + __expf(-v));
                else if (EPI == 2) v = __expf(v);
                size_t idx = (size_t)row * N + col;
                if (OUT_BF) Cb[idx] = f2bf(v);
                else        Cf[idx] = v;
            }
        }
    }
}

// ---------------- scan pass A: per-chunk sums (bf16 in, 16B loads) ----------------
__global__ __launch_bounds__(256)
void scan_partials(const ushort* __restrict__ ke, const ushort* __restrict__ ev,
                   float* __restrict__ pke, float* __restrict__ pkv) {
    const int H = 1024, S = 8192, CHUNK = 32, BH = 4096;
    int c  = blockIdx.x * 2 + (threadIdx.x >> 7);
    int h0 = (threadIdx.x & 127) * 8;
    int b  = blockIdx.y;
    size_t base = ((size_t)b * S + (size_t)c * CHUNK) * H + h0;
    float se[8] = {}, sv[8] = {};
    for (int s = 0; s < CHUNK; s++) {
        u16x8 e8 = *(const u16x8*)(ke + base + (size_t)s * H);
        u16x8 v8 = *(const u16x8*)(ev + base + (size_t)s * H);
        #pragma unroll
        for (int i = 0; i < 8; i++) {
            float e = bf2f(e8[i]);
            se[i] += e;
            sv[i] += e * bf2f(v8[i]);
        }
    }
    size_t p = (size_t)c * BH + b * H + h0;
    *(float4*)(pke + p)     = make_float4(se[0], se[1], se[2], se[3]);
    *(float4*)(pke + p + 4) = make_float4(se[4], se[5], se[6], se[7]);
    *(float4*)(pkv + p)     = make_float4(sv[0], sv[1], sv[2], sv[3]);
    *(float4*)(pkv + p + 4) = make_float4(sv[4], sv[5], sv[6], sv[7]);
}

// ---------------- scan pass B: exclusive prefix over chunks ----------------
__global__ __launch_bounds__(256)
void scan_offsets(float* __restrict__ pke, float* __restrict__ pkv, int nch, int BH) {
    int i = blockIdx.x * blockDim.x + threadIdx.x;
    if (i >= BH) return;
    float rke = 0.f, rkv = 0.f;
    for (int c = 0; c < nch; c++) {
        size_t idx = (size_t)c * BH + i;
        float a = pke[idx], b = pkv[idx];
        pke[idx] = rke; pkv[idx] = rkv;
        rke += a; rkv += b;
    }
}

// ---------------- scan pass C: inclusive scan + y = sigmoid(emb_q)*(kv/ke) ----------------
__global__ __launch_bounds__(256)
void scan_final(const ushort* __restrict__ ke, const ushort* __restrict__ ev,
                const ushort* __restrict__ sq,
                const float* __restrict__ pke, const float* __restrict__ pkv,
                ushort* __restrict__ ybf) {
    const int H = 1024, S = 8192, CHUNK = 32, BH = 4096;
    int c  = blockIdx.x * 2 + (threadIdx.x >> 7);
    int h0 = (threadIdx.x & 127) * 8;
    int b  = blockIdx.y;
    size_t p = (size_t)c * BH + b * H + h0;
    float rke[8], rkv[8];
    *(float4*)(rke)     = *(const float4*)(pke + p);
    *(float4*)(rke + 4) = *(const float4*)(pke + p + 4);
    *(float4*)(rkv)     = *(const float4*)(pkv + p);
    *(float4*)(rkv + 4) = *(const float4*)(pkv + p + 4);
    size_t base = ((size_t)b * S + (size_t)c * CHUNK) * H + h0;
    for (int s = 0; s < CHUNK; s++) {
        size_t idx = base + (size_t)s * H;
        u16x8 e8 = *(const u16x8*)(ke + idx);
        u16x8 v8 = *(const u16x8*)(ev + idx);
        u16x8 q8 = *(const u16x8*)(sq + idx);
        u16x8 o;
        #pragma unroll
        for (int i = 0; i < 8; i++) {
            float e = bf2f(e8[i]);
            rke[i] += e;
            rkv[i] += e * bf2f(v8[i]);
            o[i] = f2bf(bf2f(q8[i]) * (rkv[i] / rke[i]));
        }
        *(u16x8*)(ybf + idx) = o;
    }
}

extern "C" void kernel_launch(void* const* d_in, const int* in_sizes, int n_in,
                              void* d_out, int out_size, void* d_ws, size_t ws_size,
                              hipStream_t stream) {
    const float* q   = (const float*)d_in[0];
    const float* k   = (const float*)d_in[1];
    const float* v   = (const float*)d_in[2];
    const float* w_q = (const float*)d_in[3];
    const float* w_k = (const float*)d_in[4];
    const float* w_v = (const float*)d_in[5];
    const float* w_p = (const float*)d_in[6];
    float* out = (float*)d_out;

    const int B = 4, S = 8192, H = 1024;
    const int M = B * S;                  // 32768
    const size_t MH = (size_t)M * H;      // 33,554,432
    const int NCH = 256;                  // CHUNK = 32
    const int BH = B * H;                 // 4096

    char* ws = (char*)d_ws;
    size_t off = 0;
    auto alloc = [&](size_t bytes) -> char* {
        char* p = ws + off;
        off += (bytes + 255) & ~(size_t)255;
        return p;
    };
    ushort* qb   = (ushort*)alloc(MH * 2);     // bf16 q
    ushort* kb_  = (ushort*)alloc(MH * 2);     // bf16 k
    ushort* vb   = (ushort*)alloc(MH * 2);     // bf16 v
    ushort* wqt  = (ushort*)alloc((size_t)H * H * 2);
    ushort* wkt  = (ushort*)alloc((size_t)H * H * 2);
    ushort* wvt  = (ushort*)alloc((size_t)H * H * 2);
    ushort* wpt  = (ushort*)alloc((size_t)H * H * 2);
    ushort* sqb  = (ushort*)alloc(MH * 2);
    ushort* keb  = (ushort*)alloc(MH * 2);
    ushort* evb  = (ushort*)alloc(MH * 2);
    float*  pke  = (float*)alloc((size_t)NCH * BH * 4);
    float*  pkv  = (float*)alloc((size_t)NCH * BH * 4);

    const int ngg = (M / 256) * (H / 128);   // 1024 blocks, swizzled in-kernel
    dim3 tg(H / 32, H / 32, 4);
    dim3 gs(NCH / 2, B);
    dim3 gc(2048, 3);
    const int n8 = (int)(MH / 8);

    transpose4_to_bf16<<<tg, 256, 0, stream>>>(w_q, w_k, w_v, w_p, wqt, wkt, wvt, wpt);

    // one dispatch converts q,k,v to bf16
    cvt3_f32_bf16<<<gc, 256, 0, stream>>>((const float4*)q, (const float4*)k,
                                          (const float4*)v,
                                          (u16x8*)qb, (u16x8*)kb_, (u16x8*)vb, n8);

    // projections (fused epilogues, bf16 C)
    gemm256x128<1, 1><<<ngg, 256, 0, stream>>>(qb,  wqt, sqb);
    gemm256x128<2, 1><<<ngg, 256, 0, stream>>>(kb_, wkt, keb);
    gemm256x128<0, 1><<<ngg, 256, 0, stream>>>(vb,  wvt, evb);

    // hierarchical scan over S
    scan_partials<<<gs, 256, 0, stream>>>(keb, evb, pke, pkv);
    scan_offsets<<<BH / 256, 256, 0, stream>>>(pke, pkv, NCH, BH);
    scan_final<<<gs, 256, 0, stream>>>(keb, evb, sqb, pke, pkv, qb);   // y -> qb (reuse)

    // out = y @ w_p (fp32 out)
    gemm256x128<0, 0><<<ngg, 256, 0, stream>>>(qb, wpt, out);
}

// Round 11
// 523.558 us; speedup vs baseline: 1.4090x; 1.1465x over previous
//
#include <hip/hip_runtime.h>
#include <hip/hip_bf16.h>
#include <cstdint>

#define AS_GLOBAL __attribute__((address_space(1)))
#define AS_LDS    __attribute__((address_space(3)))

typedef __attribute__((ext_vector_type(8))) short bf16x8;
typedef __attribute__((ext_vector_type(8))) unsigned short u16x8;
typedef __attribute__((ext_vector_type(4))) float f32x4;

static __device__ __forceinline__ ushort f2bf(float x) {
    union { float f; uint32_t u; } c;
    c.f = x;
    uint32_t u = c.u;
    u += 0x7fffu + ((u >> 16) & 1u);   // RTNE
    return (ushort)(u >> 16);
}
static __device__ __forceinline__ float bf2f(ushort u) {
    union { uint32_t i; float f; } c;
    c.i = ((uint32_t)u) << 16;
    return c.f;
}

// async global->LDS, 16B/lane. Dest = wave-uniform base + lane*16.
static __device__ __forceinline__ void gload_lds16(const void* g, void* l) {
    __builtin_amdgcn_global_load_lds(
        (const AS_GLOBAL uint32_t*)(uintptr_t)g,
        (AS_LDS uint32_t*)(uint32_t)(uintptr_t)l,
        16, 0, 0);
}

// ---------------- fp32 -> bf16 convert (r8-proven: one tensor per dispatch) ----------------
__global__ __launch_bounds__(256)
void cvt_f32_bf16(const float4* __restrict__ in, u16x8* __restrict__ out, int n8) {
    int i = blockIdx.x * 256 + threadIdx.x;
    int stride = gridDim.x * 256;
    for (; i < n8; i += stride) {
        float4 a = in[i * 2], b = in[i * 2 + 1];
        u16x8 o;
        o[0] = f2bf(a.x); o[1] = f2bf(a.y); o[2] = f2bf(a.z); o[3] = f2bf(a.w);
        o[4] = f2bf(b.x); o[5] = f2bf(b.y); o[6] = f2bf(b.z); o[7] = f2bf(b.w);
        out[i] = o;
    }
}

// ---------------- [K,N] fp32 -> [N,K] bf16 transpose (4 weights, z-indexed) ----------------
__global__ __launch_bounds__(256)
void transpose4_to_bf16(const float* __restrict__ w0, const float* __restrict__ w1,
                        const float* __restrict__ w2, const float* __restrict__ w3,
                        ushort* __restrict__ t0, ushort* __restrict__ t1,
                        ushort* __restrict__ t2, ushort* __restrict__ t3) {
    const int K = 1024, N = 1024;
    __shared__ float tile[32][33];
    const float* w; ushort* wt;
    switch (blockIdx.z) {
        case 0: w = w0; wt = t0; break;
        case 1: w = w1; wt = t1; break;
        case 2: w = w2; wt = t2; break;
        default: w = w3; wt = t3; break;
    }
    int bn = blockIdx.x * 32;
    int bk = blockIdx.y * 32;
    int tx = threadIdx.x & 31, ty = threadIdx.x >> 5;
    #pragma unroll
    for (int i = 0; i < 32; i += 8)
        tile[ty + i][tx] = w[(size_t)(bk + ty + i) * N + bn + tx];
    __syncthreads();
    #pragma unroll
    for (int i = 0; i < 32; i += 8)
        wt[(size_t)(bn + ty + i) * K + bk + tx] = f2bf(tile[tx][ty + i]);
}

// =====================================================================
// 256x128 GEMM, 4 waves (2M x 2N), wave tile 128x64, BK=32 (r10-proven).
// gload_lds both operands, 3-deep ring staged 2 ahead, counted vmcnt(6),
// XOR-slot swizzle (0 conflicts), lgkmcnt(0) + one barrier per step.
// LDS 72KB -> 2 blocks/CU (register-locked: acc=128 needs 256-reg budget).
// C[M,1024] = A[M,1024](bf16) * Bt[1024,1024](bf16).
// EPI: 0=none 1=sigmoid 2=exp.  OUT_BF: bf16 C.
// =====================================================================
template<int EPI, int OUT_BF>
__global__ __launch_bounds__(256, 2)
void gemm256x128(const ushort* __restrict__ A, const ushort* __restrict__ Bt,
                 void* __restrict__ Cv) {
    constexpr int K = 1024, N = 1024;
    __shared__ alignas(16) ushort sA[3 * 8192];   // 3 x 16KB (256 rows x 32)
    __shared__ alignas(16) ushort sB[3 * 4096];   // 3 x 8KB  (128 rows x 32)
    const int tid  = threadIdx.x;
    const int wid  = tid >> 6;
    const int lane = tid & 63;
    const int wr = wid >> 1, wc = wid & 1;        // 2x2 waves; wave tile 128x64
    const int lr = lane & 15;
    const int kb = lane >> 4;                     // logical k-slot 0..3
    const int xs = (lr >> 1) & 3;                 // read-side XOR

    // XCD-locality swizzle: 1024 wgs = 8 xcds x 128.
    const int wg = blockIdx.x;
    const int xcd = wg & 7, local = wg >> 3;
    const int bm = xcd * 16 + (local >> 3);
    const int bn = local & 7;
    const int m0 = bm * 256, n0 = bn * 128;

    f32x4 acc[8][4] = {};

    auto stage = [&](int tile, int buf) {
        const int kt0 = tile * 32;
        ushort* dA = &sA[buf * 8192];
        ushort* dB = &sB[buf * 4096];
        #pragma unroll
        for (int j = 0; j < 4; j++) {
            int c = j * 256 + tid;
            int r = c >> 2, p = c & 3;
            int s = p ^ ((r >> 1) & 3);
            gload_lds16(A + (size_t)(m0 + r) * K + kt0 + s * 8, dA + c * 8);
        }
        #pragma unroll
        for (int j = 0; j < 2; j++) {
            int c = j * 256 + tid;
            int r = c >> 2, p = c & 3;
            int s = p ^ ((r >> 1) & 3);
            gload_lds16(Bt + (size_t)(n0 + r) * K + kt0 + s * 8, dB + c * 8);
        }
    };
    auto compute = [&](int buf) {
        const ushort* pA = &sA[buf * 8192];
        const ushort* pB = &sB[buf * 4096];
        bf16x8 af[8], bv[4];
        #pragma unroll
        for (int m = 0; m < 8; m++)
            af[m] = *(const bf16x8*)&pA[(wr * 128 + m * 16 + lr) * 32 + (kb ^ xs) * 8];
        #pragma unroll
        for (int n = 0; n < 4; n++)
            bv[n] = *(const bf16x8*)&pB[(wc * 64 + n * 16 + lr) * 32 + (kb ^ xs) * 8];
        #pragma unroll
        for (int m = 0; m < 8; m++)
            #pragma unroll
            for (int n = 0; n < 4; n++)
                acc[m][n] = __builtin_amdgcn_mfma_f32_16x16x32_bf16(af[m], bv[n], acc[m][n], 0, 0, 0);
    };

    // ---- prologue ----
    stage(0, 0);
    stage(1, 1);
    asm volatile("s_waitcnt vmcnt(6)" ::: "memory");
    __builtin_amdgcn_s_barrier();
    asm volatile("" ::: "memory");

    // ---- main loop: 32 K-steps, one barrier each ----
    for (int t = 0; t < 32; t++) {
        if (t < 30) stage(t + 2, (t + 2) % 3);
        compute(t % 3);
        if (t < 30)       asm volatile("s_waitcnt vmcnt(6)" ::: "memory");
        else if (t == 30) asm volatile("s_waitcnt vmcnt(0)" ::: "memory");
        asm volatile("s_waitcnt lgkmcnt(0)" ::: "memory");
        __builtin_amdgcn_s_barrier();
        asm volatile("" ::: "memory");
    }

    // ---- epilogue (C/D: col=lane&15, row=(lane>>4)*4+r) ----
    float*  Cf = (float*)Cv;
    ushort* Cb = (ushort*)Cv;
    #pragma unroll
    for (int m = 0; m < 8; m++) {
        #pragma unroll
        for (int n = 0; n < 4; n++) {
            #pragma unroll
            for (int r = 0; r < 4; r++) {
                int row = m0 + wr * 128 + m * 16 + (lane >> 4) * 4 + r;
                int col = n0 + wc * 64 + n * 16 + (lane & 15);
                float v = acc[m][n][r];
                if (EPI == 1) v = 1.0f / (1.0f + __expf(-v));
                else if (EPI == 2) v = __expf(v);
                size_t idx = (size_t)row * N + col;
                if (OUT_BF) Cb[idx] = f2bf(v);
                else        Cf[idx] = v;
            }
        }
    }
}

// ---------------- scan pass A: per-chunk sums (bf16 in, 16B loads) ----------------
__global__ __launch_bounds__(256)
void scan_partials(const ushort* __restrict__ ke, const ushort* __restrict__ ev,
                   float* __restrict__ pke, float* __restrict__ pkv) {
    const int H = 1024, S = 8192, CHUNK = 32, BH = 4096;
    int c  = blockIdx.x * 2 + (threadIdx.x >> 7);
    int h0 = (threadIdx.x & 127) * 8;
    int b  = blockIdx.y;
    size_t base = ((size_t)b * S + (size_t)c * CHUNK) * H + h0;
    float se[8] = {}, sv[8] = {};
    for (int s = 0; s < CHUNK; s++) {
        u16x8 e8 = *(const u16x8*)(ke + base + (size_t)s * H);
        u16x8 v8 = *(const u16x8*)(ev + base + (size_t)s * H);
        #pragma unroll
        for (int i = 0; i < 8; i++) {
            float e = bf2f(e8[i]);
            se[i] += e;
            sv[i] += e * bf2f(v8[i]);
        }
    }
    size_t p = (size_t)c * BH + b * H + h0;
    *(float4*)(pke + p)     = make_float4(se[0], se[1], se[2], se[3]);
    *(float4*)(pke + p + 4) = make_float4(se[4], se[5], se[6], se[7]);
    *(float4*)(pkv + p)     = make_float4(sv[0], sv[1], sv[2], sv[3]);
    *(float4*)(pkv + p + 4) = make_float4(sv[4], sv[5], sv[6], sv[7]);
}

// ---------------- scan pass B: exclusive prefix over chunks (unrolled loads) ----------------
__global__ __launch_bounds__(256)
void scan_offsets(float* __restrict__ pke, float* __restrict__ pkv, int nch, int BH) {
    int i = blockIdx.x * blockDim.x + threadIdx.x;
    if (i >= BH) return;
    float rke = 0.f, rkv = 0.f;
    #pragma unroll 8
    for (int c = 0; c < nch; c++) {
        size_t idx = (size_t)c * BH + i;
        float a = pke[idx], b = pkv[idx];
        pke[idx] = rke; pkv[idx] = rkv;
        rke += a; rkv += b;
    }
}

// ---------------- scan pass C: inclusive scan + y = sigmoid(emb_q)*(kv/ke) ----------------
__global__ __launch_bounds__(256)
void scan_final(const ushort* __restrict__ ke, const ushort* __restrict__ ev,
                const ushort* __restrict__ sq,
                const float* __restrict__ pke, const float* __restrict__ pkv,
                ushort* __restrict__ ybf) {
    const int H = 1024, S = 8192, CHUNK = 32, BH = 4096;
    int c  = blockIdx.x * 2 + (threadIdx.x >> 7);
    int h0 = (threadIdx.x & 127) * 8;
    int b  = blockIdx.y;
    size_t p = (size_t)c * BH + b * H + h0;
    float rke[8], rkv[8];
    *(float4*)(rke)     = *(const float4*)(pke + p);
    *(float4*)(rke + 4) = *(const float4*)(pke + p + 4);
    *(float4*)(rkv)     = *(const float4*)(pkv + p);
    *(float4*)(rkv + 4) = *(const float4*)(pkv + p + 4);
    size_t base = ((size_t)b * S + (size_t)c * CHUNK) * H + h0;
    for (int s = 0; s < CHUNK; s++) {
        size_t idx = base + (size_t)s * H;
        u16x8 e8 = *(const u16x8*)(ke + idx);
        u16x8 v8 = *(const u16x8*)(ev + idx);
        u16x8 q8 = *(const u16x8*)(sq + idx);
        u16x8 o;
        #pragma unroll
        for (int i = 0; i < 8; i++) {
            float e = bf2f(e8[i]);
            rke[i] += e;
            rkv[i] += e * bf2f(v8[i]);
            o[i] = f2bf(bf2f(q8[i]) * (rkv[i] / rke[i]));
        }
        *(u16x8*)(ybf + idx) = o;
    }
}

extern "C" void kernel_launch(void* const* d_in, const int* in_sizes, int n_in,
                              void* d_out, int out_size, void* d_ws, size_t ws_size,
                              hipStream_t stream) {
    const float* q   = (const float*)d_in[0];
    const float* k   = (const float*)d_in[1];
    const float* v   = (const float*)d_in[2];
    const float* w_q = (const float*)d_in[3];
    const float* w_k = (const float*)d_in[4];
    const float* w_v = (const float*)d_in[5];
    const float* w_p = (const float*)d_in[6];
    float* out = (float*)d_out;

    const int B = 4, S = 8192, H = 1024;
    const int M = B * S;                  // 32768
    const size_t MH = (size_t)M * H;      // 33,554,432
    const int NCH = 256;                  // CHUNK = 32
    const int BH = B * H;                 // 4096

    char* ws = (char*)d_ws;
    size_t off = 0;
    auto alloc = [&](size_t bytes) -> char* {
        char* p = ws + off;
        off += (bytes + 255) & ~(size_t)255;
        return p;
    };
    ushort* abuf = (ushort*)alloc(MH * 2);     // bf16 staging for q/k/v/y (reused serially)
    ushort* wqt  = (ushort*)alloc((size_t)H * H * 2);
    ushort* wkt  = (ushort*)alloc((size_t)H * H * 2);
    ushort* wvt  = (ushort*)alloc((size_t)H * H * 2);
    ushort* wpt  = (ushort*)alloc((size_t)H * H * 2);
    ushort* sqb  = (ushort*)alloc(MH * 2);
    ushort* keb  = (ushort*)alloc(MH * 2);
    ushort* evb  = (ushort*)alloc(MH * 2);
    float*  pke  = (float*)alloc((size_t)NCH * BH * 4);
    float*  pkv  = (float*)alloc((size_t)NCH * BH * 4);

    const int ngg = (M / 256) * (H / 128);   // 1024 blocks, swizzled in-kernel
    dim3 tg(H / 32, H / 32, 4);
    dim3 gs(NCH / 2, B);
    const int n8 = (int)(MH / 8);

    transpose4_to_bf16<<<tg, 256, 0, stream>>>(w_q, w_k, w_v, w_p, wqt, wkt, wvt, wpt);

    // sq = sigmoid(q @ w_q)   — one tensor in flight per cvt (L3-friendly streaming)
    cvt_f32_bf16<<<2048, 256, 0, stream>>>((const float4*)q, (u16x8*)abuf, n8);
    gemm256x128<1, 1><<<ngg, 256, 0, stream>>>(abuf, wqt, sqb);
    // ke = exp(k @ w_k)
    cvt_f32_bf16<<<2048, 256, 0, stream>>>((const float4*)k, (u16x8*)abuf, n8);
    gemm256x128<2, 1><<<ngg, 256, 0, stream>>>(abuf, wkt, keb);
    // ev = v @ w_v
    cvt_f32_bf16<<<2048, 256, 0, stream>>>((const float4*)v, (u16x8*)abuf, n8);
    gemm256x128<0, 1><<<ngg, 256, 0, stream>>>(abuf, wvt, evb);

    // hierarchical scan over S
    scan_partials<<<gs, 256, 0, stream>>>(keb, evb, pke, pkv);
    scan_offsets<<<BH / 256, 256, 0, stream>>>(pke, pkv, NCH, BH);
    scan_final<<<gs, 256, 0, stream>>>(keb, evb, sqb, pke, pkv, abuf);

    // out = y @ w_p (fp32 out)
    gemm256x128<0, 0><<<ngg, 256, 0, stream>>>(abuf, wpt, out);
}